// Round 6
// baseline (2788.812 us; speedup 1.0000x reference)
//
#include <hip/hip_runtime.h>

typedef unsigned short ushort_t;
typedef __attribute__((ext_vector_type(4))) float f32x4;
typedef __attribute__((ext_vector_type(8))) short bf16x8;
typedef __attribute__((ext_vector_type(4))) unsigned short u16x4;

#define MFMA(a, b, c) __builtin_amdgcn_mfma_f32_16x16x32_bf16((a), (b), (c), 0, 0, 0)

__device__ __forceinline__ unsigned short f2bf(float f) {
    unsigned int u = __builtin_bit_cast(unsigned int, f);
    u += 0x7fffu + ((u >> 16) & 1u);   // round-to-nearest-even
    return (unsigned short)(u >> 16);
}
__device__ __forceinline__ float bf2f(unsigned short h) {
    unsigned int u = ((unsigned int)h) << 16;
    return __builtin_bit_cast(float, u);
}
__device__ __forceinline__ void split2(float f, unsigned short& h, unsigned short& l) {
    h = f2bf(f);
    l = f2bf(f - bf2f(h));
}

// ---- Prep: transpose W (K x N) -> T (N x K) and split into bf16 hi/lo ----
__global__ __launch_bounds__(256) void wsplit_kernel(const float* __restrict__ W,
                                                     ushort_t* __restrict__ Thi,
                                                     ushort_t* __restrict__ Tlo,
                                                     int K, int N) {
    __shared__ float tile[64][65];
    int nb = N >> 6;
    int bx = blockIdx.x % nb;
    int by = blockIdx.x / nb;
    int n0 = bx * 64, k0 = by * 64;
    int t = threadIdx.x;
    int c4 = (t & 15) * 4;
    int rr = t >> 4;
    #pragma unroll
    for (int i = 0; i < 4; ++i) {
        int r = rr + i * 16;
        f32x4 vv = *(const f32x4*)(W + (size_t)(k0 + r) * N + n0 + c4);
        tile[r][c4 + 0] = vv[0];
        tile[r][c4 + 1] = vv[1];
        tile[r][c4 + 2] = vv[2];
        tile[r][c4 + 3] = vv[3];
    }
    __syncthreads();
    #pragma unroll
    for (int i = 0; i < 4; ++i) {
        int rn = rr + i * 16;            // local n (output row)
        u16x4 hv, lv;
        #pragma unroll
        for (int r2 = 0; r2 < 4; ++r2) {
            unsigned short hh, ll;
            split2(tile[c4 + r2][rn], hh, ll);
            hv[r2] = hh;
            lv[r2] = ll;
        }
        *(u16x4*)(Thi + (size_t)(n0 + rn) * K + k0 + c4) = hv;
        *(u16x4*)(Tlo + (size_t)(n0 + rn) * K + k0 + c4) = lv;
    }
}

// ---- Prep: per-window x (512 c x 64 n) -> xT (64 n x 512 c) bf16 hi/lo ----
__global__ __launch_bounds__(256) void xsplit_kernel(const float* __restrict__ x,
                                                     ushort_t* __restrict__ Thi,
                                                     ushort_t* __restrict__ Tlo) {
    __shared__ float tile[64][65];
    int b = blockIdx.x >> 3;
    int k0 = (blockIdx.x & 7) * 64;
    const float* W = x + (size_t)b * 32768;          // (512 x 64)
    ushort_t* Th = Thi + (size_t)b * 32768;          // (64 x 512)
    ushort_t* Tl = Tlo + (size_t)b * 32768;
    int t = threadIdx.x;
    int c4 = (t & 15) * 4;
    int rr = t >> 4;
    #pragma unroll
    for (int i = 0; i < 4; ++i) {
        int r = rr + i * 16;
        f32x4 vv = *(const f32x4*)(W + (size_t)(k0 + r) * 64 + c4);
        tile[r][c4 + 0] = vv[0];
        tile[r][c4 + 1] = vv[1];
        tile[r][c4 + 2] = vv[2];
        tile[r][c4 + 3] = vv[3];
    }
    __syncthreads();
    #pragma unroll
    for (int i = 0; i < 4; ++i) {
        int rn = rr + i * 16;            // token n
        u16x4 hv, lv;
        #pragma unroll
        for (int r2 = 0; r2 < 4; ++r2) {
            unsigned short hh, ll;
            split2(tile[c4 + r2][rn], hh, ll);
            hv[r2] = hh;
            lv[r2] = ll;
        }
        *(u16x4*)(Th + (size_t)rn * 512 + k0 + c4) = hv;
        *(u16x4*)(Tl + (size_t)rn * 512 + k0 + c4) = lv;
    }
}

// ---- Prep: gather relative-position bias into dense (H, 64, 64) f32 ----
__global__ __launch_bounds__(256) void biasM_kernel(const float* __restrict__ table,
                                                    float* __restrict__ biasM) {
    int u = blockIdx.x * 256 + threadIdx.x;   // 65536 = 16*64*64
    int h = u >> 12;
    int n = (u >> 6) & 63;
    int m = u & 63;
    int idx = ((n >> 3) - (m >> 3) + 7) * 15 + ((n & 7) - (m & 7) + 7);
    biasM[u] = table[idx * 16 + h];
}

// ---- Fused kernel: QKV proj + dual-activation attention + output proj ----
// grid 1024 (one block per window), 512 threads (8 waves).
// LDS 44KB (no x staging -> 2 blocks/CU, 4 waves/SIMD). x A-fragments read
// directly from pre-split xTh/xTl in global (L2/L3-resident). 4 barriers/head.
__global__ __launch_bounds__(512, 4) void attn_kernel(
    const ushort_t* __restrict__ xTh, const ushort_t* __restrict__ xTl,
    const ushort_t* __restrict__ WqTh, const ushort_t* __restrict__ WqTl,
    const ushort_t* __restrict__ WkvTh, const ushort_t* __restrict__ WkvTl,
    const float* __restrict__ bq, const float* __restrict__ bkv,
    const float* __restrict__ biasM, const float* __restrict__ wbl,
    const ushort_t* __restrict__ WpTh, const ushort_t* __restrict__ WpTl,
    const float* __restrict__ bp, float* __restrict__ out) {
    __shared__ char q_h[5120];       // q hi (64 rows x 80B)
    __shared__ char q_l[5120];
    __shared__ char k_h[5120];
    __shared__ char k_l[5120];
    __shared__ char v_h[4096];       // vT hi (32 rows x 128B, swizzled)
    __shared__ char v_l[4096];
    __shared__ char a_h[8192];       // attn weights (64 rows x 128B, swizzled)
    __shared__ char a_l[8192];       // total 45056 B
    char* ao_h = q_h;                // per-head attn output aliases q (post-S)
    char* ao_l = q_l;

    const int b = blockIdx.x;
    const int tid = threadIdx.x;
    const int l = tid & 63;
    const int w = tid >> 6;
    const int ln = l & 15;
    const int g = l >> 4;
    const int nt = w >> 1;           // row-tile 0..3
    const int dt = w & 1;            // d-tile 0..1
    const int nA = nt * 16 + ln;     // A-fragment row
    const int nC = nt * 16 + g * 4;  // C row base
    const int dcol = dt * 16 + ln;   // output column within 32 (d)
    const int swA = (nA & 7) << 4;

    float wb0 = wbl[0], wb1 = wbl[1];
    float wm = fmaxf(wb0, wb1);
    float e0 = __expf(wb0 - wm), e1 = __expf(wb1 - wm);
    float wt0 = e0 / (e0 + e1), wt1 = e1 / (e0 + e1);

    // x A-fragment base pointers (row nA, k-offset g*8 folded in)
    const ushort_t* pxh = xTh + ((size_t)b * 64 + nA) * 512 + g * 8;
    const ushort_t* pxl = xTl + ((size_t)b * 64 + nA) * 512 + g * 8;

    // out accumulators: acc[ctl*4+ntl][r] = out[ntl*16+g*4+r][w*64+ctl*16+ln]
    f32x4 acc[16];
    #pragma unroll
    for (int i = 0; i < 16; ++i) acc[i] = {0.f, 0.f, 0.f, 0.f};

    for (int h = 0; h < 16; ++h) {
        // ---------- Q-compute: q,k,v = xf @ W (+bias); global-only, no LDS ----
        const int cq = h * 32 + dcol;
        float bqv = bq[cq];
        float bkvv = bkv[cq];
        float bvv = bkv[512 + cq];
        const ushort_t* pqh = WqTh + (size_t)cq * 512 + g * 8;
        const ushort_t* pql = WqTl + (size_t)cq * 512 + g * 8;
        const ushort_t* pkh = WkvTh + (size_t)cq * 512 + g * 8;
        const ushort_t* pkl = WkvTl + (size_t)cq * 512 + g * 8;
        const ushort_t* pvh = WkvTh + (size_t)(512 + cq) * 512 + g * 8;
        const ushort_t* pvl = WkvTl + (size_t)(512 + cq) * 512 + g * 8;

        f32x4 aq = {0.f, 0.f, 0.f, 0.f};
        f32x4 ak2 = {0.f, 0.f, 0.f, 0.f};
        f32x4 av = {0.f, 0.f, 0.f, 0.f};
        #pragma unroll
        for (int kk = 0; kk < 16; ++kk) {
            const int k0 = kk * 32;
            bf16x8 Ah = *(const bf16x8*)(pxh + k0);
            bf16x8 Al = *(const bf16x8*)(pxl + k0);
            bf16x8 Bh = *(const bf16x8*)(pqh + k0);
            bf16x8 Bl = *(const bf16x8*)(pql + k0);
            aq = MFMA(Ah, Bh, aq);
            aq = MFMA(Ah, Bl, aq);
            aq = MFMA(Al, Bh, aq);
            Bh = *(const bf16x8*)(pkh + k0);
            Bl = *(const bf16x8*)(pkl + k0);
            ak2 = MFMA(Ah, Bh, ak2);
            ak2 = MFMA(Ah, Bl, ak2);
            ak2 = MFMA(Al, Bh, ak2);
            Bh = *(const bf16x8*)(pvh + k0);
            Bl = *(const bf16x8*)(pvl + k0);
            av = MFMA(Ah, Bh, av);
            av = MFMA(Ah, Bl, av);
            av = MFMA(Al, Bh, av);
        }

        __syncthreads();   // B0: prev head's proj ao-reads done before stores

        // store q (pre-scaled), k as (token, d) rows of 80B
        #pragma unroll
        for (int r = 0; r < 4; ++r) {
            int nr = nC + r;
            unsigned short hh, ll;
            split2((aq[r] + bqv) * 0.17677669529663689f, hh, ll);
            *(unsigned short*)(q_h + nr * 80 + 2 * dcol) = hh;
            *(unsigned short*)(q_l + nr * 80 + 2 * dcol) = ll;
            split2(ak2[r] + bkvv, hh, ll);
            *(unsigned short*)(k_h + nr * 80 + 2 * dcol) = hh;
            *(unsigned short*)(k_l + nr * 80 + 2 * dcol) = ll;
        }
        // store v transposed (d, token), swizzled, packed 4x bf16
        {
            u16x4 vh4, vl4;
            #pragma unroll
            for (int r = 0; r < 4; ++r) {
                unsigned short hh, ll;
                split2(av[r] + bvv, hh, ll);
                vh4[r] = hh;
                vl4[r] = ll;
            }
            int voff = dcol * 128 + ((2 * nC) ^ ((dcol & 7) << 4));
            *(u16x4*)(v_h + voff) = vh4;
            *(u16x4*)(v_l + voff) = vl4;
        }
        __syncthreads();   // B1: q/k/v ready

        // ---------- S-phase: s = q k^T + bias; dual softmax/relu^2; a-store ----
        if (w < 4) {
            f32x4 sv[4];
            float ex[4][4];
            float rinv0[4];
            int offq = (w * 16 + ln) * 80 + 16 * g;
            bf16x8 Qh = *(const bf16x8*)(q_h + offq);
            bf16x8 Ql = *(const bf16x8*)(q_l + offq);
            #pragma unroll
            for (int mt = 0; mt < 4; ++mt) {
                int offk = (mt * 16 + ln) * 80 + 16 * g;
                bf16x8 Kh = *(const bf16x8*)(k_h + offk);
                bf16x8 Kl = *(const bf16x8*)(k_l + offk);
                f32x4 s = {0.f, 0.f, 0.f, 0.f};
                s = MFMA(Qh, Kh, s);
                s = MFMA(Qh, Kl, s);
                s = MFMA(Ql, Kh, s);
                sv[mt] = s;
            }
            const float* bM = biasM + h * 4096;
            #pragma unroll
            for (int r = 0; r < 4; ++r) {
                int n_ = w * 16 + g * 4 + r;
                #pragma unroll
                for (int mt = 0; mt < 4; ++mt)
                    sv[mt][r] += bM[n_ * 64 + mt * 16 + ln];
            }
            #pragma unroll
            for (int r = 0; r < 4; ++r) {
                float mx = fmaxf(fmaxf(sv[0][r], sv[1][r]), fmaxf(sv[2][r], sv[3][r]));
                mx = fmaxf(mx, __shfl_xor(mx, 1));
                mx = fmaxf(mx, __shfl_xor(mx, 2));
                mx = fmaxf(mx, __shfl_xor(mx, 4));
                mx = fmaxf(mx, __shfl_xor(mx, 8));
                float sum = 0.f;
                #pragma unroll
                for (int mt = 0; mt < 4; ++mt) {
                    float e = __expf(sv[mt][r] - mx);
                    ex[mt][r] = e;
                    sum += e;
                }
                sum += __shfl_xor(sum, 1);
                sum += __shfl_xor(sum, 2);
                sum += __shfl_xor(sum, 4);
                sum += __shfl_xor(sum, 8);
                rinv0[r] = wt0 / sum;
            }
            #pragma unroll
            for (int mt = 0; mt < 4; ++mt) {
                int m_ = mt * 16 + ln;
                #pragma unroll
                for (int r = 0; r < 4; ++r) {
                    int n_ = w * 16 + g * 4 + r;
                    float rl = fmaxf(sv[mt][r], 0.f);
                    float aval = ex[mt][r] * rinv0[r] + wt1 * rl * rl;
                    unsigned short hh, ll;
                    split2(aval, hh, ll);
                    int aoff = n_ * 128 + ((2 * m_) ^ ((n_ & 7) << 4));
                    *(unsigned short*)(a_h + aoff) = hh;
                    *(unsigned short*)(a_l + aoff) = ll;
                }
            }
        }
        __syncthreads();   // B2: a ready (q/k reads also complete)

        // ---------- PV: ao = a @ v ----------
        f32x4 ao = {0.f, 0.f, 0.f, 0.f};
        {
            const int swV = (dcol & 7) << 4;
            #pragma unroll
            for (int ks = 0; ks < 2; ++ks) {
                int mo = 2 * (ks * 32 + g * 8);
                bf16x8 Aa = *(const bf16x8*)(a_h + nA * 128 + (mo ^ swA));
                bf16x8 Ab = *(const bf16x8*)(a_l + nA * 128 + (mo ^ swA));
                bf16x8 Vh = *(const bf16x8*)(v_h + dcol * 128 + (mo ^ swV));
                bf16x8 Vl = *(const bf16x8*)(v_l + dcol * 128 + (mo ^ swV));
                ao = MFMA(Aa, Vh, ao);
                ao = MFMA(Aa, Vl, ao);
                ao = MFMA(Ab, Vh, ao);
            }
        }
        // ao -> LDS (hi/lo, 80B rows, aliases dead q region; no barrier needed:
        // q reads finished before B2)
        #pragma unroll
        for (int r = 0; r < 4; ++r) {
            unsigned short hh, ll;
            split2(ao[r], hh, ll);
            *(unsigned short*)(ao_h + (nC + r) * 80 + 2 * dcol) = hh;
            *(unsigned short*)(ao_l + (nC + r) * 80 + 2 * dcol) = ll;
        }
        __syncthreads();   // B3: ao ready

        // ---------- proj accumulate: out += ao_head @ Wp[head k-slice] ----------
        // Wave w owns out col-tiles [w*64, w*64+64); B-fragment loaded once and
        // reused across all 4 n-tiles (Wp fetched exactly once per block).
        {
            bf16x8 Ah[4], Al[4];
            #pragma unroll
            for (int ntl = 0; ntl < 4; ++ntl) {
                int offa = (ntl * 16 + ln) * 80 + 16 * g;
                Ah[ntl] = *(const bf16x8*)(ao_h + offa);
                Al[ntl] = *(const bf16x8*)(ao_l + offa);
            }
            const ushort_t* ph = WpTh + (size_t)(w * 64 + ln) * 512 + h * 32 + g * 8;
            const ushort_t* pl = WpTl + (size_t)(w * 64 + ln) * 512 + h * 32 + g * 8;
            #pragma unroll
            for (int ctl = 0; ctl < 4; ++ctl) {
                bf16x8 Bh = *(const bf16x8*)(ph + (size_t)ctl * 8192);
                bf16x8 Bl = *(const bf16x8*)(pl + (size_t)ctl * 8192);
                #pragma unroll
                for (int ntl = 0; ntl < 4; ++ntl) {
                    acc[ctl * 4 + ntl] = MFMA(Ah[ntl], Bh, acc[ctl * 4 + ntl]);
                    acc[ctl * 4 + ntl] = MFMA(Ah[ntl], Bl, acc[ctl * 4 + ntl]);
                    acc[ctl * 4 + ntl] = MFMA(Al[ntl], Bh, acc[ctl * 4 + ntl]);
                }
            }
        }
        // no barrier here: next head's Q-compute touches no LDS; B0 protects stores
    }

    // ---------- epilogue: add bias, store out (B, C, N) ----------
    #pragma unroll
    for (int ctl = 0; ctl < 4; ++ctl) {
        int cout = w * 64 + ctl * 16 + ln;
        float bb = bp[cout];
        #pragma unroll
        for (int ntl = 0; ntl < 4; ++ntl) {
            f32x4 o;
            #pragma unroll
            for (int r = 0; r < 4; ++r) o[r] = acc[ctl * 4 + ntl][r] + bb;
            *(f32x4*)(out + ((size_t)b * 512 + cout) * 64 + ntl * 16 + g * 4) = o;
        }
    }
}

extern "C" void kernel_launch(void* const* d_in, const int* in_sizes, int n_in,
                              void* d_out, int out_size, void* d_ws, size_t ws_size,
                              hipStream_t stream) {
    const float* x = (const float*)d_in[0];
    const float* Wq = (const float*)d_in[1];
    const float* bq = (const float*)d_in[2];
    const float* Wkv = (const float*)d_in[3];
    const float* bkv = (const float*)d_in[4];
    const float* btab = (const float*)d_in[5];
    const float* wbl = (const float*)d_in[6];
    const float* Wp = (const float*)d_in[7];
    const float* bp = (const float*)d_in[8];
    float* out = (float*)d_out;

    char* ws = (char*)d_ws;
    // ws layout (bytes)
    ushort_t* WqTh = (ushort_t*)(ws + 0);          //  512x512 bf16 = 512KB
    ushort_t* WqTl = (ushort_t*)(ws + 524288);
    ushort_t* WkvTh = (ushort_t*)(ws + 1048576);   // 1024x512 bf16 = 1MB
    ushort_t* WkvTl = (ushort_t*)(ws + 2097152);
    ushort_t* WpTh = (ushort_t*)(ws + 3145728);
    ushort_t* WpTl = (ushort_t*)(ws + 3670016);
    float* biasM = (float*)(ws + 4194304);         // 16x64x64 f32 = 256KB
    ushort_t* xTh = (ushort_t*)(ws + 4456448);     // 1024x64x512 bf16 = 64MB
    ushort_t* xTl = (ushort_t*)(ws + 71565312);    // 64MB -> total ~132.7MB

    wsplit_kernel<<<64, 256, 0, stream>>>(Wq, WqTh, WqTl, 512, 512);
    wsplit_kernel<<<128, 256, 0, stream>>>(Wkv, WkvTh, WkvTl, 512, 1024);
    wsplit_kernel<<<64, 256, 0, stream>>>(Wp, WpTh, WpTl, 512, 512);
    biasM_kernel<<<256, 256, 0, stream>>>(btab, biasM);
    xsplit_kernel<<<8192, 256, 0, stream>>>(x, xTh, xTl);

    attn_kernel<<<1024, 512, 0, stream>>>(xTh, xTl, WqTh, WqTl, WkvTh, WkvTl,
                                          bq, bkv, biasM, wbl,
                                          WpTh, WpTl, bp, out);
}

// Round 7
// 2144.142 us; speedup vs baseline: 1.3007x; 1.3007x over previous
//
#include <hip/hip_runtime.h>

typedef unsigned short ushort_t;
typedef __attribute__((ext_vector_type(4))) float f32x4;
typedef __attribute__((ext_vector_type(8))) short bf16x8;
typedef __attribute__((ext_vector_type(4))) unsigned short u16x4;

#define MFMA(a, b, c) __builtin_amdgcn_mfma_f32_16x16x32_bf16((a), (b), (c), 0, 0, 0)

__device__ __forceinline__ unsigned short f2bf(float f) {
    unsigned int u = __builtin_bit_cast(unsigned int, f);
    u += 0x7fffu + ((u >> 16) & 1u);   // round-to-nearest-even
    return (unsigned short)(u >> 16);
}
__device__ __forceinline__ float bf2f(unsigned short h) {
    unsigned int u = ((unsigned int)h) << 16;
    return __builtin_bit_cast(float, u);
}
__device__ __forceinline__ void split2(float f, unsigned short& h, unsigned short& l) {
    h = f2bf(f);
    l = f2bf(f - bf2f(h));
}

// Stage a (512 c x 64 n) f32 c-major matrix into LDS as (64 rows x 512 cols)
// bf16 hi/lo, rows 1024B, XOR-swizzled (row&7)<<4.
__device__ __forceinline__ void stage_split(const float* __restrict__ src,
                                            char* sh, char* sl, int tid) {
    #pragma unroll
    for (int i = 0; i < 16; ++i) {
        int u = tid + i * 512;
        int n = u & 63;
        int c0 = (u >> 6) << 2;
        u16x4 hv, lv;
        #pragma unroll
        for (int j = 0; j < 4; ++j) {
            float f = src[(size_t)(c0 + j) * 64 + n];
            unsigned short hh, ll;
            split2(f, hh, ll);
            hv[j] = hh;
            lv[j] = ll;
        }
        int off = n * 1024 + ((2 * c0) ^ ((n & 7) << 4));
        *(u16x4*)(sh + off) = hv;
        *(u16x4*)(sl + off) = lv;
    }
}

// ---- Prep: transpose W (K x N) -> T (N x K) and split into bf16 hi/lo ----
__global__ __launch_bounds__(256) void wsplit_kernel(const float* __restrict__ W,
                                                     ushort_t* __restrict__ Thi,
                                                     ushort_t* __restrict__ Tlo,
                                                     int K, int N) {
    __shared__ float tile[64][65];
    int nb = N >> 6;
    int bx = blockIdx.x % nb;
    int by = blockIdx.x / nb;
    int n0 = bx * 64, k0 = by * 64;
    int t = threadIdx.x;
    int c4 = (t & 15) * 4;
    int rr = t >> 4;
    #pragma unroll
    for (int i = 0; i < 4; ++i) {
        int r = rr + i * 16;
        f32x4 vv = *(const f32x4*)(W + (size_t)(k0 + r) * N + n0 + c4);
        tile[r][c4 + 0] = vv[0];
        tile[r][c4 + 1] = vv[1];
        tile[r][c4 + 2] = vv[2];
        tile[r][c4 + 3] = vv[3];
    }
    __syncthreads();
    #pragma unroll
    for (int i = 0; i < 4; ++i) {
        int rn = rr + i * 16;
        u16x4 hv, lv;
        #pragma unroll
        for (int r2 = 0; r2 < 4; ++r2) {
            unsigned short hh, ll;
            split2(tile[c4 + r2][rn], hh, ll);
            hv[r2] = hh;
            lv[r2] = ll;
        }
        *(u16x4*)(Thi + (size_t)(n0 + rn) * K + k0 + c4) = hv;
        *(u16x4*)(Tlo + (size_t)(n0 + rn) * K + k0 + c4) = lv;
    }
}

// ---- Prep: gather relative-position bias into dense (H, 64, 64) f32 ----
__global__ __launch_bounds__(256) void biasM_kernel(const float* __restrict__ table,
                                                    float* __restrict__ biasM) {
    int u = blockIdx.x * 256 + threadIdx.x;
    int h = u >> 12;
    int n = (u >> 6) & 63;
    int m = u & 63;
    int idx = ((n >> 3) - (m >> 3) + 7) * 15 + ((n & 7) - (m & 7) + 7);
    biasM[u] = table[idx * 16 + h];
}

// ---- Kernel A: per-window QKV projection. x staged once in LDS; the head
// loop is barrier-free (MFMA + L2-hot weight stream + fire-and-forget
// stores). Writes q/k [tok][32] planes, v [32][tok] planes (hi/lo bf16).
__global__ __launch_bounds__(512, 2) void qkv_kernel(
    const float* __restrict__ x,
    const ushort_t* __restrict__ WqTh, const ushort_t* __restrict__ WqTl,
    const ushort_t* __restrict__ WkvTh, const ushort_t* __restrict__ WkvTl,
    const float* __restrict__ bq, const float* __restrict__ bkv,
    ushort_t* __restrict__ qph, ushort_t* __restrict__ qpl,
    ushort_t* __restrict__ kph, ushort_t* __restrict__ kpl,
    ushort_t* __restrict__ vph, ushort_t* __restrict__ vpl) {
    extern __shared__ char sm[];
    char* xs_h = sm;                 // 64KB
    char* xs_l = sm + 65536;         // 64KB

    const int tid = threadIdx.x;
    stage_split(x + (size_t)blockIdx.x * 32768, xs_h, xs_l, tid);

    const int l = tid & 63;
    const int w = tid >> 6;
    const int ln = l & 15;
    const int g = l >> 4;
    const int nt = w >> 1;
    const int dt = w & 1;
    const int nA = nt * 16 + ln;
    const int nC = nt * 16 + g * 4;
    const int dcol = dt * 16 + ln;
    const int swA = (nA & 7) << 4;

    __syncthreads();

    for (int h = 0; h < 16; ++h) {
        const int cq = h * 32 + dcol;
        float bqv = bq[cq];
        float bkvv = bkv[cq];
        float bvv = bkv[512 + cq];
        const ushort_t* pqh = WqTh + (size_t)cq * 512 + g * 8;
        const ushort_t* pql = WqTl + (size_t)cq * 512 + g * 8;
        const ushort_t* pkh = WkvTh + (size_t)cq * 512 + g * 8;
        const ushort_t* pkl = WkvTl + (size_t)cq * 512 + g * 8;
        const ushort_t* pvh = WkvTh + (size_t)(512 + cq) * 512 + g * 8;
        const ushort_t* pvl = WkvTl + (size_t)(512 + cq) * 512 + g * 8;

        f32x4 aq = {0.f, 0.f, 0.f, 0.f};
        f32x4 ak2 = {0.f, 0.f, 0.f, 0.f};
        f32x4 av = {0.f, 0.f, 0.f, 0.f};
        #pragma unroll
        for (int kk = 0; kk < 16; ++kk) {
            const int k0 = kk * 32;
            int off = nA * 1024 + ((2 * (k0 + g * 8)) ^ swA);
            bf16x8 Ah = *(const bf16x8*)(xs_h + off);
            bf16x8 Al = *(const bf16x8*)(xs_l + off);
            bf16x8 Bh = *(const bf16x8*)(pqh + k0);
            bf16x8 Bl = *(const bf16x8*)(pql + k0);
            aq = MFMA(Ah, Bh, aq);
            aq = MFMA(Ah, Bl, aq);
            aq = MFMA(Al, Bh, aq);
            Bh = *(const bf16x8*)(pkh + k0);
            Bl = *(const bf16x8*)(pkl + k0);
            ak2 = MFMA(Ah, Bh, ak2);
            ak2 = MFMA(Ah, Bl, ak2);
            ak2 = MFMA(Al, Bh, ak2);
            Bh = *(const bf16x8*)(pvh + k0);
            Bl = *(const bf16x8*)(pvl + k0);
            av = MFMA(Ah, Bh, av);
            av = MFMA(Ah, Bl, av);
            av = MFMA(Al, Bh, av);
        }

        const size_t hb = (size_t)blockIdx.x * 16 + h;   // plane row group
        // q (pre-scaled) / k: [hb][tok][32], 2B stores (16-lane 32B chunks)
        #pragma unroll
        for (int r = 0; r < 4; ++r) {
            size_t o = hb * 2048 + (size_t)(nC + r) * 32 + dcol;
            unsigned short hh, ll;
            split2((aq[r] + bqv) * 0.17677669529663689f, hh, ll);
            qph[o] = hh;
            qpl[o] = ll;
            split2(ak2[r] + bkvv, hh, ll);
            kph[o] = hh;
            kpl[o] = ll;
        }
        // v transposed: [hb][d=32][tok], u16x4 (4 toks) per thread
        {
            u16x4 vh4, vl4;
            #pragma unroll
            for (int r = 0; r < 4; ++r) {
                unsigned short hh, ll;
                split2(av[r] + bvv, hh, ll);
                vh4[r] = hh;
                vl4[r] = ll;
            }
            size_t o = hb * 2048 + (size_t)dcol * 64 + nC;
            *(u16x4*)(vph + o) = vh4;
            *(u16x4*)(vpl + o) = vl4;
        }
    }
}

// ---- Kernel B: per-window attention + fused output projection.
// q/k/v read from ws planes as contiguous 16B MFMA fragments (one touch).
// LDS only 16KB (a-buffer; ao aliases it) -> 2 blocks/CU, 4 waves/SIMD.
__global__ __launch_bounds__(512, 4) void attn_kernel(
    const ushort_t* __restrict__ qph, const ushort_t* __restrict__ qpl,
    const ushort_t* __restrict__ kph, const ushort_t* __restrict__ kpl,
    const ushort_t* __restrict__ vph, const ushort_t* __restrict__ vpl,
    const float* __restrict__ biasM, const float* __restrict__ wbl,
    const ushort_t* __restrict__ WpTh, const ushort_t* __restrict__ WpTl,
    const float* __restrict__ bp, float* __restrict__ out) {
    __shared__ char a_h[8192];       // attn weights (64 rows x 128B, swizzled)
    __shared__ char a_l[8192];
    char* ao_h = a_h;                // per-head attn output aliases a (post-PV)
    char* ao_l = a_l;

    const int b = blockIdx.x;
    const int tid = threadIdx.x;
    const int l = tid & 63;
    const int w = tid >> 6;
    const int ln = l & 15;
    const int g = l >> 4;
    const int nt = w >> 1;
    const int nA = nt * 16 + ln;
    const int nC = nt * 16 + g * 4;
    const int dcol = (w & 1) * 16 + ln;
    const int swA = (nA & 7) << 4;

    float wb0 = wbl[0], wb1 = wbl[1];
    float wm = fmaxf(wb0, wb1);
    float e0 = __expf(wb0 - wm), e1 = __expf(wb1 - wm);
    float wt0 = e0 / (e0 + e1), wt1 = e1 / (e0 + e1);

    f32x4 acc[16];
    #pragma unroll
    for (int i = 0; i < 16; ++i) acc[i] = {0.f, 0.f, 0.f, 0.f};

    for (int h = 0; h < 16; ++h) {
        const size_t hb = (size_t)b * 16 + h;
        const ushort_t* qbh = qph + hb * 2048;
        const ushort_t* qbl = qpl + hb * 2048;
        const ushort_t* kbh = kph + hb * 2048;
        const ushort_t* kbl = kpl + hb * 2048;

        // ---------- S-phase: s = q k^T + bias; dual softmax/relu^2; a-store ----
        if (w < 4) {
            f32x4 sv[4];
            int offq = (w * 16 + ln) * 32 + g * 8;
            bf16x8 Qh = *(const bf16x8*)(qbh + offq);
            bf16x8 Ql = *(const bf16x8*)(qbl + offq);
            #pragma unroll
            for (int mt = 0; mt < 4; ++mt) {
                int offk = (mt * 16 + ln) * 32 + g * 8;
                bf16x8 Kh = *(const bf16x8*)(kbh + offk);
                bf16x8 Kl = *(const bf16x8*)(kbl + offk);
                f32x4 s = {0.f, 0.f, 0.f, 0.f};
                s = MFMA(Qh, Kh, s);
                s = MFMA(Qh, Kl, s);
                s = MFMA(Ql, Kh, s);
                sv[mt] = s;
            }
            const float* bM = biasM + h * 4096;
            #pragma unroll
            for (int r = 0; r < 4; ++r) {
                int n_ = w * 16 + g * 4 + r;
                #pragma unroll
                for (int mt = 0; mt < 4; ++mt)
                    sv[mt][r] += bM[n_ * 64 + mt * 16 + ln];
            }
            #pragma unroll
            for (int r = 0; r < 4; ++r) {
                int n_ = w * 16 + g * 4 + r;
                float mx = fmaxf(fmaxf(sv[0][r], sv[1][r]), fmaxf(sv[2][r], sv[3][r]));
                mx = fmaxf(mx, __shfl_xor(mx, 1));
                mx = fmaxf(mx, __shfl_xor(mx, 2));
                mx = fmaxf(mx, __shfl_xor(mx, 4));
                mx = fmaxf(mx, __shfl_xor(mx, 8));
                float ex[4];
                float sum = 0.f;
                #pragma unroll
                for (int mt = 0; mt < 4; ++mt) {
                    ex[mt] = __expf(sv[mt][r] - mx);
                    sum += ex[mt];
                }
                sum += __shfl_xor(sum, 1);
                sum += __shfl_xor(sum, 2);
                sum += __shfl_xor(sum, 4);
                sum += __shfl_xor(sum, 8);
                float rinv0 = wt0 / sum;
                #pragma unroll
                for (int mt = 0; mt < 4; ++mt) {
                    int m_ = mt * 16 + ln;
                    float rl = fmaxf(sv[mt][r], 0.f);
                    float aval = ex[mt] * rinv0 + wt1 * rl * rl;
                    unsigned short hh, ll;
                    split2(aval, hh, ll);
                    int aoff = n_ * 128 + ((2 * m_) ^ ((n_ & 7) << 4));
                    *(unsigned short*)(a_h + aoff) = hh;
                    *(unsigned short*)(a_l + aoff) = ll;
                }
            }
        }
        __syncthreads();   // B1: a ready

        // ---------- PV: ao = a @ v (v fragments straight from global) ----------
        f32x4 ao = {0.f, 0.f, 0.f, 0.f};
        {
            const ushort_t* vbh = vph + hb * 2048 + (size_t)dcol * 64;
            const ushort_t* vbl = vpl + hb * 2048 + (size_t)dcol * 64;
            #pragma unroll
            for (int ks = 0; ks < 2; ++ks) {
                int mo = ks * 32 + g * 8;
                bf16x8 Aa = *(const bf16x8*)(a_h + nA * 128 + ((2 * mo) ^ swA));
                bf16x8 Ab = *(const bf16x8*)(a_l + nA * 128 + ((2 * mo) ^ swA));
                bf16x8 Vh = *(const bf16x8*)(vbh + mo);
                bf16x8 Vl = *(const bf16x8*)(vbl + mo);
                ao = MFMA(Aa, Vh, ao);
                ao = MFMA(Aa, Vl, ao);
                ao = MFMA(Ab, Vh, ao);
            }
        }
        __syncthreads();   // B2: all a reads done before ao overwrites region

        // ---------- ao -> LDS (hi/lo, 80B rows) ----------
        #pragma unroll
        for (int r = 0; r < 4; ++r) {
            unsigned short hh, ll;
            split2(ao[r], hh, ll);
            *(unsigned short*)(ao_h + (nC + r) * 80 + 2 * dcol) = hh;
            *(unsigned short*)(ao_l + (nC + r) * 80 + 2 * dcol) = ll;
        }
        __syncthreads();   // B3: ao ready

        // ---------- proj accumulate: out += ao_head @ Wp[head k-slice] ----------
        {
            bf16x8 Ah[4], Al[4];
            #pragma unroll
            for (int ntl = 0; ntl < 4; ++ntl) {
                int offa = (ntl * 16 + ln) * 80 + 16 * g;
                Ah[ntl] = *(const bf16x8*)(ao_h + offa);
                Al[ntl] = *(const bf16x8*)(ao_l + offa);
            }
            const ushort_t* ph = WpTh + (size_t)(w * 64 + ln) * 512 + h * 32 + g * 8;
            const ushort_t* pl = WpTl + (size_t)(w * 64 + ln) * 512 + h * 32 + g * 8;
            #pragma unroll
            for (int ctl = 0; ctl < 4; ++ctl) {
                bf16x8 Bh = *(const bf16x8*)(ph + (size_t)ctl * 8192);
                bf16x8 Bl = *(const bf16x8*)(pl + (size_t)ctl * 8192);
                #pragma unroll
                for (int ntl = 0; ntl < 4; ++ntl) {
                    acc[ctl * 4 + ntl] = MFMA(Ah[ntl], Bh, acc[ctl * 4 + ntl]);
                    acc[ctl * 4 + ntl] = MFMA(Ah[ntl], Bl, acc[ctl * 4 + ntl]);
                    acc[ctl * 4 + ntl] = MFMA(Al[ntl], Bh, acc[ctl * 4 + ntl]);
                }
            }
        }
        __syncthreads();   // B4: proj ao-reads done before next head's a-store
    }

    // ---------- epilogue: add bias, store out (B, C, N) ----------
    #pragma unroll
    for (int ctl = 0; ctl < 4; ++ctl) {
        int cout = w * 64 + ctl * 16 + ln;
        float bb = bp[cout];
        #pragma unroll
        for (int ntl = 0; ntl < 4; ++ntl) {
            f32x4 o;
            #pragma unroll
            for (int r = 0; r < 4; ++r) o[r] = acc[ctl * 4 + ntl][r] + bb;
            *(f32x4*)(out + ((size_t)b * 512 + cout) * 64 + ntl * 16 + g * 4) = o;
        }
    }
}

extern "C" void kernel_launch(void* const* d_in, const int* in_sizes, int n_in,
                              void* d_out, int out_size, void* d_ws, size_t ws_size,
                              hipStream_t stream) {
    const float* x = (const float*)d_in[0];
    const float* Wq = (const float*)d_in[1];
    const float* bq = (const float*)d_in[2];
    const float* Wkv = (const float*)d_in[3];
    const float* bkv = (const float*)d_in[4];
    const float* btab = (const float*)d_in[5];
    const float* wbl = (const float*)d_in[6];
    const float* Wp = (const float*)d_in[7];
    const float* bp = (const float*)d_in[8];
    float* out = (float*)d_out;

    char* ws = (char*)d_ws;
    ushort_t* WqTh = (ushort_t*)(ws + 0);          //  512x512 bf16 = 512KB
    ushort_t* WqTl = (ushort_t*)(ws + 524288);
    ushort_t* WkvTh = (ushort_t*)(ws + 1048576);   // 1024x512 bf16 = 1MB
    ushort_t* WkvTl = (ushort_t*)(ws + 2097152);
    ushort_t* WpTh = (ushort_t*)(ws + 3145728);
    ushort_t* WpTl = (ushort_t*)(ws + 3670016);
    float* biasM = (float*)(ws + 4194304);         // 16x64x64 f32 = 256KB

    // qkv planes after 4456448; per window per plane = 16*64*32*2B = 64KB,
    // 6 planes -> 384KB/window. Choose pass count to fit ws_size.
    const size_t qbase = 4456448;
    int npass;
    if (ws_size >= qbase + (size_t)1024 * 393216) npass = 1;
    else if (ws_size >= qbase + (size_t)512 * 393216) npass = 2;
    else npass = 4;                                // 105MB, fits proven >=132MB
    const int wpp = 1024 / npass;
    const size_t P = (size_t)wpp * 65536;          // bytes per plane
    ushort_t* qph = (ushort_t*)(ws + qbase);
    ushort_t* qpl = (ushort_t*)(ws + qbase + P);
    ushort_t* kph = (ushort_t*)(ws + qbase + 2 * P);
    ushort_t* kpl = (ushort_t*)(ws + qbase + 3 * P);
    ushort_t* vph = (ushort_t*)(ws + qbase + 4 * P);
    ushort_t* vpl = (ushort_t*)(ws + qbase + 5 * P);

    wsplit_kernel<<<64, 256, 0, stream>>>(Wq, WqTh, WqTl, 512, 512);
    wsplit_kernel<<<128, 256, 0, stream>>>(Wkv, WkvTh, WkvTl, 512, 1024);
    wsplit_kernel<<<64, 256, 0, stream>>>(Wp, WpTh, WpTl, 512, 512);
    biasM_kernel<<<256, 256, 0, stream>>>(btab, biasM);

    (void)hipFuncSetAttribute((const void*)qkv_kernel,
                              hipFuncAttributeMaxDynamicSharedMemorySize, 131072);

    for (int p = 0; p < npass; ++p) {
        const float* xp = x + (size_t)p * wpp * 32768;
        float* outp = out + (size_t)p * wpp * 32768;
        qkv_kernel<<<wpp, 512, 131072, stream>>>(xp, WqTh, WqTl, WkvTh, WkvTl,
                                                 bq, bkv, qph, qpl, kph, kpl,
                                                 vph, vpl);
        attn_kernel<<<wpp, 512, 0, stream>>>(qph, qpl, kph, kpl, vph, vpl,
                                             biasM, wbl, WpTh, WpTl, bp, outp);
    }
}

// Round 8
// 1175.321 us; speedup vs baseline: 2.3728x; 1.8243x over previous
//
#include <hip/hip_runtime.h>

typedef unsigned short ushort_t;
typedef __attribute__((ext_vector_type(4))) float f32x4;
typedef __attribute__((ext_vector_type(8))) short bf16x8;
typedef __attribute__((ext_vector_type(4))) unsigned short u16x4;

#define MFMA(a, b, c) __builtin_amdgcn_mfma_f32_16x16x32_bf16((a), (b), (c), 0, 0, 0)

__device__ __forceinline__ unsigned short f2bf(float f) {
    unsigned int u = __builtin_bit_cast(unsigned int, f);
    u += 0x7fffu + ((u >> 16) & 1u);   // round-to-nearest-even
    return (unsigned short)(u >> 16);
}
__device__ __forceinline__ float bf2f(unsigned short h) {
    unsigned int u = ((unsigned int)h) << 16;
    return __builtin_bit_cast(float, u);
}
__device__ __forceinline__ void split2(float f, unsigned short& h, unsigned short& l) {
    h = f2bf(f);
    l = f2bf(f - bf2f(h));
}

__device__ __forceinline__ void gload16(const void* g, void* l) {
    __builtin_amdgcn_global_load_lds(
        (const __attribute__((address_space(1))) void*)g,
        (__attribute__((address_space(3))) void*)l, 16, 0, 0);
}

// ---- Prep: transpose W (K x N) -> T (N x K) and split into bf16 hi/lo ----
__global__ __launch_bounds__(256) void wsplit_kernel(const float* __restrict__ W,
                                                     ushort_t* __restrict__ Thi,
                                                     ushort_t* __restrict__ Tlo,
                                                     int K, int N) {
    __shared__ float tile[64][65];
    int nb = N >> 6;
    int bx = blockIdx.x % nb;
    int by = blockIdx.x / nb;
    int n0 = bx * 64, k0 = by * 64;
    int t = threadIdx.x;
    int c4 = (t & 15) * 4;
    int rr = t >> 4;
    #pragma unroll
    for (int i = 0; i < 4; ++i) {
        int r = rr + i * 16;
        f32x4 vv = *(const f32x4*)(W + (size_t)(k0 + r) * N + n0 + c4);
        tile[r][c4 + 0] = vv[0];
        tile[r][c4 + 1] = vv[1];
        tile[r][c4 + 2] = vv[2];
        tile[r][c4 + 3] = vv[3];
    }
    __syncthreads();
    #pragma unroll
    for (int i = 0; i < 4; ++i) {
        int rn = rr + i * 16;
        u16x4 hv, lv;
        #pragma unroll
        for (int r2 = 0; r2 < 4; ++r2) {
            unsigned short hh, ll;
            split2(tile[c4 + r2][rn], hh, ll);
            hv[r2] = hh;
            lv[r2] = ll;
        }
        *(u16x4*)(Thi + (size_t)(n0 + rn) * K + k0 + c4) = hv;
        *(u16x4*)(Tlo + (size_t)(n0 + rn) * K + k0 + c4) = lv;
    }
}

// ---- Prep: per-window x (512 c x 64 n) -> xT (64 n x 512 c) bf16 hi/lo ----
__global__ __launch_bounds__(256) void xsplit_kernel(const float* __restrict__ x,
                                                     ushort_t* __restrict__ Thi,
                                                     ushort_t* __restrict__ Tlo) {
    __shared__ float tile[64][65];
    int b = blockIdx.x >> 3;
    int k0 = (blockIdx.x & 7) * 64;
    const float* W = x + (size_t)b * 32768;
    ushort_t* Th = Thi + (size_t)b * 32768;
    ushort_t* Tl = Tlo + (size_t)b * 32768;
    int t = threadIdx.x;
    int c4 = (t & 15) * 4;
    int rr = t >> 4;
    #pragma unroll
    for (int i = 0; i < 4; ++i) {
        int r = rr + i * 16;
        f32x4 vv = *(const f32x4*)(W + (size_t)(k0 + r) * 64 + c4);
        tile[r][c4 + 0] = vv[0];
        tile[r][c4 + 1] = vv[1];
        tile[r][c4 + 2] = vv[2];
        tile[r][c4 + 3] = vv[3];
    }
    __syncthreads();
    #pragma unroll
    for (int i = 0; i < 4; ++i) {
        int rn = rr + i * 16;
        u16x4 hv, lv;
        #pragma unroll
        for (int r2 = 0; r2 < 4; ++r2) {
            unsigned short hh, ll;
            split2(tile[c4 + r2][rn], hh, ll);
            hv[r2] = hh;
            lv[r2] = ll;
        }
        *(u16x4*)(Th + (size_t)rn * 512 + k0 + c4) = hv;
        *(u16x4*)(Tl + (size_t)rn * 512 + k0 + c4) = lv;
    }
}

// ---- Prep: gather relative-position bias into dense (H, 64, 64) f32 ----
__global__ __launch_bounds__(256) void biasM_kernel(const float* __restrict__ table,
                                                    float* __restrict__ biasM) {
    int u = blockIdx.x * 256 + threadIdx.x;
    int h = u >> 12;
    int n = (u >> 6) & 63;
    int m = u & 63;
    int idx = ((n >> 3) - (m >> 3) + 7) * 15 + ((n & 7) - (m & 7) + 7);
    biasM[u] = table[idx * 16 + h];
}

// Stage one 16KB tile (128 rows x 64 k, bf16) from row-major [R][512] src into
// LDS with row-XOR swizzle, via global_load_lds width 16 (pre-swizzled source).
__device__ __forceinline__ void stage_tile(const ushort_t* __restrict__ src,
                                           int rbase, int k0, char* lds, int t) {
    #pragma unroll
    for (int c = 0; c < 4; ++c) {
        int row = c * 32 + (t >> 3);
        int kb = ((t & 7) * 16) ^ ((row & 7) << 4);   // swizzled byte offset
        const ushort_t* g = src + (size_t)(rbase + row) * 512 + k0 + (kb >> 1);
        gload16(g, lds + c * 4096 + t * 16);
    }
}

// ---- QKV GEMM: C[65536 tok x 1536 cols] = xT @ [WqT;WkvT], hi/lo 3-MFMA ----
// 128x128 tile, BK=64, 4 waves, 64KB LDS, global_load_lds staging, 2 blk/CU.
// Epilogue: bias (+scale for q), split to bf16 hi/lo q/k/v planes
// [win*16+head][tok][32].
__global__ __launch_bounds__(256, 2) void qkv_gemm(
    const ushort_t* __restrict__ xTh, const ushort_t* __restrict__ xTl,
    const ushort_t* __restrict__ BTh, const ushort_t* __restrict__ BTl,
    const float* __restrict__ bq, const float* __restrict__ bkv,
    ushort_t* __restrict__ qph, ushort_t* __restrict__ qpl,
    ushort_t* __restrict__ kph, ushort_t* __restrict__ kpl,
    ushort_t* __restrict__ vph, ushort_t* __restrict__ vpl,
    int gm) {
    extern __shared__ char sm[];
    char* As_h = sm;             // 16KB: 128 rows x 128B (64 k), swizzled
    char* As_l = sm + 16384;
    char* Bs_h = sm + 32768;     // 16KB: 128 cols x 128B (64 k), swizzled
    char* Bs_l = sm + 49152;

    // XCD-bijective chunked swizzle: consecutive wg share an N-panel per XCD
    int nb = gm * 12;
    int qq = nb >> 3, r8 = nb & 7;
    int xcd = blockIdx.x & 7, pos = blockIdx.x >> 3;
    int wg = (xcd < r8 ? xcd * (qq + 1) : r8 * (qq + 1) + (xcd - r8) * qq) + pos;
    int nt = wg / gm;
    int mt = wg - nt * gm;
    const int m0 = mt * 128;
    const int n0 = nt * 128;

    const int t = threadIdx.x;
    const int l = t & 63;
    const int w = t >> 6;
    const int ln = l & 15;
    const int g = l >> 4;
    const int wm = w >> 1;       // row-half
    const int wn = w & 1;        // col-half

    f32x4 acc[4][4];
    #pragma unroll
    for (int i = 0; i < 4; ++i)
        #pragma unroll
        for (int j = 0; j < 4; ++j) acc[i][j] = {0.f, 0.f, 0.f, 0.f};

    for (int ks = 0; ks < 8; ++ks) {
        const int k0 = ks * 64;
        stage_tile(xTh, m0, k0, As_h, t);
        stage_tile(xTl, m0, k0, As_l, t);
        stage_tile(BTh, n0, k0, Bs_h, t);
        stage_tile(BTl, n0, k0, Bs_l, t);
        __syncthreads();                       // drains vmcnt(0): tiles ready
        #pragma unroll
        for (int kf = 0; kf < 2; ++kf) {
            const int kb = kf * 64 + g * 16;
            bf16x8 Ah[4], Al[4];
            #pragma unroll
            for (int fi = 0; fi < 4; ++fi) {
                int row = wm * 64 + fi * 16 + ln;
                int off = row * 128 + (kb ^ ((row & 7) << 4));
                Ah[fi] = *(const bf16x8*)(As_h + off);
                Al[fi] = *(const bf16x8*)(As_l + off);
            }
            #pragma unroll
            for (int fj = 0; fj < 4; ++fj) {
                int cl = wn * 64 + fj * 16 + ln;
                int off = cl * 128 + (kb ^ ((cl & 7) << 4));
                bf16x8 Bh = *(const bf16x8*)(Bs_h + off);
                bf16x8 Bl = *(const bf16x8*)(Bs_l + off);
                #pragma unroll
                for (int fi = 0; fi < 4; ++fi) {
                    acc[fi][fj] = MFMA(Ah[fi], Bh, acc[fi][fj]);
                    acc[fi][fj] = MFMA(Ah[fi], Bl, acc[fi][fj]);
                    acc[fi][fj] = MFMA(Al[fi], Bh, acc[fi][fj]);
                }
            }
        }
        __syncthreads();                       // reads done before next stage
    }

    // epilogue: bias/scale, split, scatter to q/k/v planes
    const int g4 = g * 4;
    #pragma unroll
    for (int fj = 0; fj < 4; ++fj) {
        int col = n0 + wn * 64 + fj * 16 + ln;
        int which = col >> 9;                  // 0=q 1=k 2=v
        float bias = (which == 0) ? bq[col] : bkv[col - 512];
        float scl = (which == 0) ? 0.17677669529663689f : 1.f;
        int head = (col >> 5) & 15;
        int d = col & 31;
        ushort_t* ph = (which == 0) ? qph : (which == 1) ? kph : vph;
        ushort_t* pl = (which == 0) ? qpl : (which == 1) ? kpl : vpl;
        #pragma unroll
        for (int fi = 0; fi < 4; ++fi) {
            #pragma unroll
            for (int r = 0; r < 4; ++r) {
                int m = m0 + wm * 64 + fi * 16 + g4 + r;
                size_t off = (((size_t)(m >> 6) * 16 + head) * 64 + (m & 63)) * 32 + d;
                unsigned short hh, ll;
                split2((acc[fi][fj][r] + bias) * scl, hh, ll);
                ph[off] = hh;
                pl[off] = ll;
            }
        }
    }
}

// ---- attention + fused output projection (per window) ----
// q/k read from planes; v staged into swizzled LDS by waves 4..7 during the
// S-phase (overlap). LDS 24KB -> 2 blocks/CU, 4 waves/SIMD.
__global__ __launch_bounds__(512, 4) void attn_kernel(
    const ushort_t* __restrict__ qph, const ushort_t* __restrict__ qpl,
    const ushort_t* __restrict__ kph, const ushort_t* __restrict__ kpl,
    const ushort_t* __restrict__ vph, const ushort_t* __restrict__ vpl,
    const float* __restrict__ biasM, const float* __restrict__ wbl,
    const ushort_t* __restrict__ WpTh, const ushort_t* __restrict__ WpTl,
    const float* __restrict__ bp, float* __restrict__ out) {
    __shared__ char a_h[8192];       // attn weights (64 rows x 128B, swizzled)
    __shared__ char a_l[8192];
    __shared__ char v_h[4096];       // vT (32 d-rows x 128B, swizzled)
    __shared__ char v_l[4096];
    char* ao_h = a_h;                // per-head attn output aliases a (post-PV)
    char* ao_l = a_l;

    const int b = blockIdx.x;
    const int tid = threadIdx.x;
    const int l = tid & 63;
    const int w = tid >> 6;
    const int ln = l & 15;
    const int g = l >> 4;
    const int nt = w >> 1;
    const int nA = nt * 16 + ln;
    const int nC = nt * 16 + g * 4;
    const int dcol = (w & 1) * 16 + ln;
    const int swA = (nA & 7) << 4;

    float wb0 = wbl[0], wb1 = wbl[1];
    float wm = fmaxf(wb0, wb1);
    float e0 = __expf(wb0 - wm), e1 = __expf(wb1 - wm);
    float wt0 = e0 / (e0 + e1), wt1 = e1 / (e0 + e1);

    f32x4 acc[16];
    #pragma unroll
    for (int i = 0; i < 16; ++i) acc[i] = {0.f, 0.f, 0.f, 0.f};

    for (int h = 0; h < 16; ++h) {
        const size_t hb = (size_t)b * 16 + h;

        // ---------- S-phase (waves 0..3) | v-stage (waves 4..7) ----------
        if (w < 4) {
            const ushort_t* qbh = qph + hb * 2048;
            const ushort_t* qbl = qpl + hb * 2048;
            const ushort_t* kbh = kph + hb * 2048;
            const ushort_t* kbl = kpl + hb * 2048;
            f32x4 sv[4];
            int offq = (w * 16 + ln) * 32 + g * 8;
            bf16x8 Qh = *(const bf16x8*)(qbh + offq);
            bf16x8 Ql = *(const bf16x8*)(qbl + offq);
            #pragma unroll
            for (int mt = 0; mt < 4; ++mt) {
                int offk = (mt * 16 + ln) * 32 + g * 8;
                bf16x8 Kh = *(const bf16x8*)(kbh + offk);
                bf16x8 Kl = *(const bf16x8*)(kbl + offk);
                f32x4 s = {0.f, 0.f, 0.f, 0.f};
                s = MFMA(Qh, Kh, s);
                s = MFMA(Qh, Kl, s);
                s = MFMA(Ql, Kh, s);
                sv[mt] = s;
            }
            const float* bM = biasM + h * 4096;
            #pragma unroll
            for (int r = 0; r < 4; ++r) {
                int n_ = w * 16 + g * 4 + r;
                #pragma unroll
                for (int mt = 0; mt < 4; ++mt)
                    sv[mt][r] += bM[n_ * 64 + mt * 16 + ln];
            }
            #pragma unroll
            for (int r = 0; r < 4; ++r) {
                int n_ = w * 16 + g * 4 + r;
                float mx = fmaxf(fmaxf(sv[0][r], sv[1][r]), fmaxf(sv[2][r], sv[3][r]));
                mx = fmaxf(mx, __shfl_xor(mx, 1));
                mx = fmaxf(mx, __shfl_xor(mx, 2));
                mx = fmaxf(mx, __shfl_xor(mx, 4));
                mx = fmaxf(mx, __shfl_xor(mx, 8));
                float ex[4];
                float sum = 0.f;
                #pragma unroll
                for (int mt = 0; mt < 4; ++mt) {
                    ex[mt] = __expf(sv[mt][r] - mx);
                    sum += ex[mt];
                }
                sum += __shfl_xor(sum, 1);
                sum += __shfl_xor(sum, 2);
                sum += __shfl_xor(sum, 4);
                sum += __shfl_xor(sum, 8);
                float rinv0 = wt0 / sum;
                #pragma unroll
                for (int mt = 0; mt < 4; ++mt) {
                    int m_ = mt * 16 + ln;
                    float rl = fmaxf(sv[mt][r], 0.f);
                    float aval = ex[mt] * rinv0 + wt1 * rl * rl;
                    unsigned short hh, ll;
                    split2(aval, hh, ll);
                    int aoff = n_ * 128 + ((2 * m_) ^ ((n_ & 7) << 4));
                    *(unsigned short*)(a_h + aoff) = hh;
                    *(unsigned short*)(a_l + aoff) = ll;
                }
            }
        } else {
            // stage v[tok][32] -> v_lds[d][tok] (swizzled), 16B loads
            int t2 = tid - 256;                  // 0..255
            bf16x8 vh8 = *(const bf16x8*)(vph + hb * 2048 + t2 * 8);
            bf16x8 vl8 = *(const bf16x8*)(vpl + hb * 2048 + t2 * 8);
            int tok = t2 >> 2;
            int d0 = (t2 & 3) * 8;
            #pragma unroll
            for (int j = 0; j < 8; ++j) {
                int d = d0 + j;
                int off = d * 128 + ((tok * 2) ^ ((d & 7) << 4));
                *(unsigned short*)(v_h + off) = (unsigned short)vh8[j];
                *(unsigned short*)(v_l + off) = (unsigned short)vl8[j];
            }
        }
        __syncthreads();   // B1: a + v_lds ready

        // ---------- PV: ao = a @ v ----------
        f32x4 ao = {0.f, 0.f, 0.f, 0.f};
        {
            const int swV = (dcol & 7) << 4;
            #pragma unroll
            for (int ks = 0; ks < 2; ++ks) {
                int mo = 2 * (ks * 32 + g * 8);
                bf16x8 Aa = *(const bf16x8*)(a_h + nA * 128 + (mo ^ swA));
                bf16x8 Ab = *(const bf16x8*)(a_l + nA * 128 + (mo ^ swA));
                bf16x8 Vh = *(const bf16x8*)(v_h + dcol * 128 + (mo ^ swV));
                bf16x8 Vl = *(const bf16x8*)(v_l + dcol * 128 + (mo ^ swV));
                ao = MFMA(Aa, Vh, ao);
                ao = MFMA(Aa, Vl, ao);
                ao = MFMA(Ab, Vh, ao);
            }
        }
        __syncthreads();   // B2: a reads done before ao overwrites region

        // ---------- ao -> LDS (hi/lo, 80B rows) ----------
        #pragma unroll
        for (int r = 0; r < 4; ++r) {
            unsigned short hh, ll;
            split2(ao[r], hh, ll);
            *(unsigned short*)(ao_h + (nC + r) * 80 + 2 * dcol) = hh;
            *(unsigned short*)(ao_l + (nC + r) * 80 + 2 * dcol) = ll;
        }
        __syncthreads();   // B3: ao ready

        // ---------- proj accumulate: out += ao_head @ Wp[head k-slice] ----------
        {
            bf16x8 Ah[4], Al[4];
            #pragma unroll
            for (int ntl = 0; ntl < 4; ++ntl) {
                int offa = (ntl * 16 + ln) * 80 + 16 * g;
                Ah[ntl] = *(const bf16x8*)(ao_h + offa);
                Al[ntl] = *(const bf16x8*)(ao_l + offa);
            }
            const ushort_t* ph = WpTh + (size_t)(w * 64 + ln) * 512 + h * 32 + g * 8;
            const ushort_t* pl = WpTl + (size_t)(w * 64 + ln) * 512 + h * 32 + g * 8;
            #pragma unroll
            for (int ctl = 0; ctl < 4; ++ctl) {
                bf16x8 Bh = *(const bf16x8*)(ph + (size_t)ctl * 8192);
                bf16x8 Bl = *(const bf16x8*)(pl + (size_t)ctl * 8192);
                #pragma unroll
                for (int ntl = 0; ntl < 4; ++ntl) {
                    acc[ctl * 4 + ntl] = MFMA(Ah[ntl], Bh, acc[ctl * 4 + ntl]);
                    acc[ctl * 4 + ntl] = MFMA(Ah[ntl], Bl, acc[ctl * 4 + ntl]);
                    acc[ctl * 4 + ntl] = MFMA(Al[ntl], Bh, acc[ctl * 4 + ntl]);
                }
            }
        }
        __syncthreads();   // B4: proj ao-reads done before next head's stores
    }

    // ---------- epilogue: add bias, store out (B, C, N) ----------
    #pragma unroll
    for (int ctl = 0; ctl < 4; ++ctl) {
        int cout = w * 64 + ctl * 16 + ln;
        float bb = bp[cout];
        #pragma unroll
        for (int ntl = 0; ntl < 4; ++ntl) {
            f32x4 o;
            #pragma unroll
            for (int r = 0; r < 4; ++r) o[r] = acc[ctl * 4 + ntl][r] + bb;
            *(f32x4*)(out + ((size_t)b * 512 + cout) * 64 + ntl * 16 + g * 4) = o;
        }
    }
}

extern "C" void kernel_launch(void* const* d_in, const int* in_sizes, int n_in,
                              void* d_out, int out_size, void* d_ws, size_t ws_size,
                              hipStream_t stream) {
    const float* x = (const float*)d_in[0];
    const float* Wq = (const float*)d_in[1];
    const float* bq = (const float*)d_in[2];
    const float* Wkv = (const float*)d_in[3];
    const float* bkv = (const float*)d_in[4];
    const float* btab = (const float*)d_in[5];
    const float* wbl = (const float*)d_in[6];
    const float* Wp = (const float*)d_in[7];
    const float* bp = (const float*)d_in[8];
    float* out = (float*)d_out;

    char* ws = (char*)d_ws;
    // B = [WqT rows 0..511 ; WkvT rows 512..1535], hi/lo planes
    ushort_t* BTh = (ushort_t*)(ws + 0);           // 1536x512x2B = 1.5MB
    ushort_t* BTl = (ushort_t*)(ws + 1572864);
    ushort_t* WpTh = (ushort_t*)(ws + 3145728);
    ushort_t* WpTl = (ushort_t*)(ws + 3670016);
    float* biasM = (float*)(ws + 4194304);         // 256KB -> 4456448

    const size_t qbase = 4456448;
    const size_t perwin = 524288;   // xT hi/lo 128KB + 6 planes 384KB
    int npass;
    if (ws_size >= qbase + 1024 * perwin) npass = 1;        // 541MB
    else if (ws_size >= qbase + 512 * perwin) npass = 2;    // 273MB (proven fits)
    else npass = 4;                                         // 139MB
    const int wpp = 1024 / npass;
    const size_t C = (size_t)wpp * 65536;
    ushort_t* xTh = (ushort_t*)(ws + qbase);
    ushort_t* xTl = (ushort_t*)(ws + qbase + C);
    ushort_t* qph = (ushort_t*)(ws + qbase + 2 * C);
    ushort_t* qpl = (ushort_t*)(ws + qbase + 3 * C);
    ushort_t* kph = (ushort_t*)(ws + qbase + 4 * C);
    ushort_t* kpl = (ushort_t*)(ws + qbase + 5 * C);
    ushort_t* vph = (ushort_t*)(ws + qbase + 6 * C);
    ushort_t* vpl = (ushort_t*)(ws + qbase + 7 * C);

    wsplit_kernel<<<64, 256, 0, stream>>>(Wq, BTh, BTl, 512, 512);
    wsplit_kernel<<<128, 256, 0, stream>>>(Wkv, BTh + (size_t)512 * 512,
                                           BTl + (size_t)512 * 512, 512, 1024);
    wsplit_kernel<<<64, 256, 0, stream>>>(Wp, WpTh, WpTl, 512, 512);
    biasM_kernel<<<256, 256, 0, stream>>>(btab, biasM);

    (void)hipFuncSetAttribute((const void*)qkv_gemm,
                              hipFuncAttributeMaxDynamicSharedMemorySize, 65536);

    const int gm = wpp / 2;          // M-tiles per pass (128 tokens each)
    for (int p = 0; p < npass; ++p) {
        xsplit_kernel<<<wpp * 8, 256, 0, stream>>>(x + (size_t)p * wpp * 32768,
                                                   xTh, xTl);
        qkv_gemm<<<gm * 12, 256, 65536, stream>>>(xTh, xTl, BTh, BTl, bq, bkv,
                                                  qph, qpl, kph, kpl, vph, vpl,
                                                  gm);
        attn_kernel<<<wpp, 512, 0, stream>>>(qph, qpl, kph, kpl, vph, vpl,
                                             biasM, wbl, WpTh, WpTl, bp,
                                             out + (size_t)p * wpp * 32768);
    }
}

// Round 9
// 1006.708 us; speedup vs baseline: 2.7702x; 1.1675x over previous
//
#include <hip/hip_runtime.h>

typedef unsigned short ushort_t;
typedef __attribute__((ext_vector_type(4))) float f32x4;
typedef __attribute__((ext_vector_type(8))) short bf16x8;
typedef __attribute__((ext_vector_type(4))) unsigned short u16x4;

#define MFMA(a, b, c) __builtin_amdgcn_mfma_f32_16x16x32_bf16((a), (b), (c), 0, 0, 0)

__device__ __forceinline__ unsigned short f2bf(float f) {
    unsigned int u = __builtin_bit_cast(unsigned int, f);
    u += 0x7fffu + ((u >> 16) & 1u);   // round-to-nearest-even
    return (unsigned short)(u >> 16);
}
__device__ __forceinline__ float bf2f(unsigned short h) {
    unsigned int u = ((unsigned int)h) << 16;
    return __builtin_bit_cast(float, u);
}
__device__ __forceinline__ void split2(float f, unsigned short& h, unsigned short& l) {
    h = f2bf(f);
    l = f2bf(f - bf2f(h));
}

__device__ __forceinline__ void gload16(const void* g, void* l) {
    __builtin_amdgcn_global_load_lds(
        (const __attribute__((address_space(1))) void*)g,
        (__attribute__((address_space(3))) void*)l, 16, 0, 0);
}

// ---- Prep: transpose W (K x N) -> T (N x K) and split into bf16 hi/lo ----
__global__ __launch_bounds__(256) void wsplit_kernel(const float* __restrict__ W,
                                                     ushort_t* __restrict__ Thi,
                                                     ushort_t* __restrict__ Tlo,
                                                     int K, int N) {
    __shared__ float tile[64][65];
    int nb = N >> 6;
    int bx = blockIdx.x % nb;
    int by = blockIdx.x / nb;
    int n0 = bx * 64, k0 = by * 64;
    int t = threadIdx.x;
    int c4 = (t & 15) * 4;
    int rr = t >> 4;
    #pragma unroll
    for (int i = 0; i < 4; ++i) {
        int r = rr + i * 16;
        f32x4 vv = *(const f32x4*)(W + (size_t)(k0 + r) * N + n0 + c4);
        tile[r][c4 + 0] = vv[0];
        tile[r][c4 + 1] = vv[1];
        tile[r][c4 + 2] = vv[2];
        tile[r][c4 + 3] = vv[3];
    }
    __syncthreads();
    #pragma unroll
    for (int i = 0; i < 4; ++i) {
        int rn = rr + i * 16;
        u16x4 hv, lv;
        #pragma unroll
        for (int r2 = 0; r2 < 4; ++r2) {
            unsigned short hh, ll;
            split2(tile[c4 + r2][rn], hh, ll);
            hv[r2] = hh;
            lv[r2] = ll;
        }
        *(u16x4*)(Thi + (size_t)(n0 + rn) * K + k0 + c4) = hv;
        *(u16x4*)(Tlo + (size_t)(n0 + rn) * K + k0 + c4) = lv;
    }
}

// ---- Prep: per-window x (512 c x 64 n) -> xT (64 n x 512 c) bf16 hi/lo ----
__global__ __launch_bounds__(256) void xsplit_kernel(const float* __restrict__ x,
                                                     ushort_t* __restrict__ Thi,
                                                     ushort_t* __restrict__ Tlo) {
    __shared__ float tile[64][65];
    int b = blockIdx.x >> 3;
    int k0 = (blockIdx.x & 7) * 64;
    const float* W = x + (size_t)b * 32768;
    ushort_t* Th = Thi + (size_t)b * 32768;
    ushort_t* Tl = Tlo + (size_t)b * 32768;
    int t = threadIdx.x;
    int c4 = (t & 15) * 4;
    int rr = t >> 4;
    #pragma unroll
    for (int i = 0; i < 4; ++i) {
        int r = rr + i * 16;
        f32x4 vv = *(const f32x4*)(W + (size_t)(k0 + r) * 64 + c4);
        tile[r][c4 + 0] = vv[0];
        tile[r][c4 + 1] = vv[1];
        tile[r][c4 + 2] = vv[2];
        tile[r][c4 + 3] = vv[3];
    }
    __syncthreads();
    #pragma unroll
    for (int i = 0; i < 4; ++i) {
        int rn = rr + i * 16;
        u16x4 hv, lv;
        #pragma unroll
        for (int r2 = 0; r2 < 4; ++r2) {
            unsigned short hh, ll;
            split2(tile[c4 + r2][rn], hh, ll);
            hv[r2] = hh;
            lv[r2] = ll;
        }
        *(u16x4*)(Th + (size_t)rn * 512 + k0 + c4) = hv;
        *(u16x4*)(Tl + (size_t)rn * 512 + k0 + c4) = lv;
    }
}

// ---- Prep: gather relative-position bias into dense (H, 64, 64) f32 ----
__global__ __launch_bounds__(256) void biasM_kernel(const float* __restrict__ table,
                                                    float* __restrict__ biasM) {
    int u = blockIdx.x * 256 + threadIdx.x;
    int h = u >> 12;
    int n = (u >> 6) & 63;
    int m = u & 63;
    int idx = ((n >> 3) - (m >> 3) + 7) * 15 + ((n & 7) - (m & 7) + 7);
    biasM[u] = table[idx * 16 + h];
}

// Stage one 16KB tile (128 rows x 64 k, bf16) from row-major [R][512] src into
// LDS with row-XOR swizzle, via global_load_lds width 16 (pre-swizzled source).
__device__ __forceinline__ void stage_tile(const ushort_t* __restrict__ src,
                                           int rbase, int k0, char* lds, int t) {
    #pragma unroll
    for (int c = 0; c < 4; ++c) {
        int row = c * 32 + (t >> 3);
        int kb = ((t & 7) * 16) ^ ((row & 7) << 4);   // swizzled byte offset
        const ushort_t* g = src + (size_t)(rbase + row) * 512 + k0 + (kb >> 1);
        gload16(g, lds + c * 4096 + t * 16);
    }
}

// ---- QKV GEMM: C[M tok x 1536 cols] = xT @ [WqT;WkvT], hi/lo 3-MFMA ----
// Epilogue: bias (+scale q), split, scatter. q/k planes [hb][tok][32];
// v plane PRE-SWIZZLED: [hb] blob, ushort off = d*64 + (tok ^ ((d&7)<<3)),
// so attn can global_load_lds it linearly and read swizzled.
__global__ __launch_bounds__(256, 2) void qkv_gemm(
    const ushort_t* __restrict__ xTh, const ushort_t* __restrict__ xTl,
    const ushort_t* __restrict__ BTh, const ushort_t* __restrict__ BTl,
    const float* __restrict__ bq, const float* __restrict__ bkv,
    ushort_t* __restrict__ qph, ushort_t* __restrict__ qpl,
    ushort_t* __restrict__ kph, ushort_t* __restrict__ kpl,
    ushort_t* __restrict__ vph, ushort_t* __restrict__ vpl,
    int gm) {
    extern __shared__ char sm[];
    char* As_h = sm;
    char* As_l = sm + 16384;
    char* Bs_h = sm + 32768;
    char* Bs_l = sm + 49152;

    int nb = gm * 12;
    int qq = nb >> 3, r8 = nb & 7;
    int xcd = blockIdx.x & 7, pos = blockIdx.x >> 3;
    int wg = (xcd < r8 ? xcd * (qq + 1) : r8 * (qq + 1) + (xcd - r8) * qq) + pos;
    int nt = wg / gm;
    int mt = wg - nt * gm;
    const int m0 = mt * 128;
    const int n0 = nt * 128;

    const int t = threadIdx.x;
    const int l = t & 63;
    const int w = t >> 6;
    const int ln = l & 15;
    const int g = l >> 4;
    const int wm = w >> 1;
    const int wn = w & 1;

    f32x4 acc[4][4];
    #pragma unroll
    for (int i = 0; i < 4; ++i)
        #pragma unroll
        for (int j = 0; j < 4; ++j) acc[i][j] = {0.f, 0.f, 0.f, 0.f};

    for (int ks = 0; ks < 8; ++ks) {
        const int k0 = ks * 64;
        stage_tile(xTh, m0, k0, As_h, t);
        stage_tile(xTl, m0, k0, As_l, t);
        stage_tile(BTh, n0, k0, Bs_h, t);
        stage_tile(BTl, n0, k0, Bs_l, t);
        __syncthreads();
        #pragma unroll
        for (int kf = 0; kf < 2; ++kf) {
            const int kb = kf * 64 + g * 16;
            bf16x8 Ah[4], Al[4];
            #pragma unroll
            for (int fi = 0; fi < 4; ++fi) {
                int row = wm * 64 + fi * 16 + ln;
                int off = row * 128 + (kb ^ ((row & 7) << 4));
                Ah[fi] = *(const bf16x8*)(As_h + off);
                Al[fi] = *(const bf16x8*)(As_l + off);
            }
            #pragma unroll
            for (int fj = 0; fj < 4; ++fj) {
                int cl = wn * 64 + fj * 16 + ln;
                int off = cl * 128 + (kb ^ ((cl & 7) << 4));
                bf16x8 Bh = *(const bf16x8*)(Bs_h + off);
                bf16x8 Bl = *(const bf16x8*)(Bs_l + off);
                #pragma unroll
                for (int fi = 0; fi < 4; ++fi) {
                    acc[fi][fj] = MFMA(Ah[fi], Bh, acc[fi][fj]);
                    acc[fi][fj] = MFMA(Ah[fi], Bl, acc[fi][fj]);
                    acc[fi][fj] = MFMA(Al[fi], Bh, acc[fi][fj]);
                }
            }
        }
        __syncthreads();
    }

    const int g4 = g * 4;
    #pragma unroll
    for (int fj = 0; fj < 4; ++fj) {
        int col = n0 + wn * 64 + fj * 16 + ln;
        int which = col >> 9;                  // 0=q 1=k 2=v
        float bias = (which == 0) ? bq[col] : bkv[col - 512];
        float scl = (which == 0) ? 0.17677669529663689f : 1.f;
        int head = (col >> 5) & 15;
        int d = col & 31;
        ushort_t* ph = (which == 0) ? qph : (which == 1) ? kph : vph;
        ushort_t* pl = (which == 0) ? qpl : (which == 1) ? kpl : vpl;
        #pragma unroll
        for (int fi = 0; fi < 4; ++fi) {
            #pragma unroll
            for (int r = 0; r < 4; ++r) {
                int m = m0 + wm * 64 + fi * 16 + g4 + r;
                int tok = m & 63;
                size_t hb = (size_t)(m >> 6) * 16 + head;
                size_t off = (which == 2)
                    ? hb * 2048 + d * 64 + (tok ^ ((d & 7) << 3))
                    : hb * 2048 + tok * 32 + d;
                unsigned short hh, ll;
                split2((acc[fi][fj][r] + bias) * scl, hh, ll);
                ph[off] = hh;
                pl[off] = ll;
            }
        }
    }
}

// ---- proj GEMM: out[b][c][n] = ao[M x 512] @ WpT + bp, f32 output ----
__global__ __launch_bounds__(256, 2) void proj_gemm(
    const ushort_t* __restrict__ Ah_, const ushort_t* __restrict__ Al_,
    const ushort_t* __restrict__ Bh_, const ushort_t* __restrict__ Bl_,
    const float* __restrict__ bp, float* __restrict__ out, int gm) {
    extern __shared__ char sm[];
    char* As_h = sm;
    char* As_l = sm + 16384;
    char* Bs_h = sm + 32768;
    char* Bs_l = sm + 49152;

    int nb = gm * 4;
    int qq = nb >> 3, r8 = nb & 7;
    int xcd = blockIdx.x & 7, pos = blockIdx.x >> 3;
    int wg = (xcd < r8 ? xcd * (qq + 1) : r8 * (qq + 1) + (xcd - r8) * qq) + pos;
    int nt = wg / gm;
    int mt = wg - nt * gm;
    const int m0 = mt * 128;
    const int n0 = nt * 128;

    const int t = threadIdx.x;
    const int l = t & 63;
    const int w = t >> 6;
    const int ln = l & 15;
    const int g = l >> 4;
    const int wm = w >> 1;
    const int wn = w & 1;

    f32x4 acc[4][4];
    #pragma unroll
    for (int i = 0; i < 4; ++i)
        #pragma unroll
        for (int j = 0; j < 4; ++j) acc[i][j] = {0.f, 0.f, 0.f, 0.f};

    for (int ks = 0; ks < 8; ++ks) {
        const int k0 = ks * 64;
        stage_tile(Ah_, m0, k0, As_h, t);
        stage_tile(Al_, m0, k0, As_l, t);
        stage_tile(Bh_, n0, k0, Bs_h, t);
        stage_tile(Bl_, n0, k0, Bs_l, t);
        __syncthreads();
        #pragma unroll
        for (int kf = 0; kf < 2; ++kf) {
            const int kb = kf * 64 + g * 16;
            bf16x8 Ah[4], Al[4];
            #pragma unroll
            for (int fi = 0; fi < 4; ++fi) {
                int row = wm * 64 + fi * 16 + ln;
                int off = row * 128 + (kb ^ ((row & 7) << 4));
                Ah[fi] = *(const bf16x8*)(As_h + off);
                Al[fi] = *(const bf16x8*)(As_l + off);
            }
            #pragma unroll
            for (int fj = 0; fj < 4; ++fj) {
                int cl = wn * 64 + fj * 16 + ln;
                int off = cl * 128 + (kb ^ ((cl & 7) << 4));
                bf16x8 Bh = *(const bf16x8*)(Bs_h + off);
                bf16x8 Bl = *(const bf16x8*)(Bs_l + off);
                #pragma unroll
                for (int fi = 0; fi < 4; ++fi) {
                    acc[fi][fj] = MFMA(Ah[fi], Bh, acc[fi][fj]);
                    acc[fi][fj] = MFMA(Ah[fi], Bl, acc[fi][fj]);
                    acc[fi][fj] = MFMA(Al[fi], Bh, acc[fi][fj]);
                }
            }
        }
        __syncthreads();
    }

    const int g4 = g * 4;
    #pragma unroll
    for (int fj = 0; fj < 4; ++fj) {
        int col = n0 + wn * 64 + fj * 16 + ln;
        float bias = bp[col];
        #pragma unroll
        for (int fi = 0; fi < 4; ++fi) {
            int m = m0 + wm * 64 + fi * 16 + g4;
            f32x4 o;
            #pragma unroll
            for (int r = 0; r < 4; ++r) o[r] = acc[fi][fj][r] + bias;
            *(f32x4*)(out + ((size_t)(m >> 6) * 512 + col) * 64 + (m & 63)) = o;
        }
    }
}

// ---- attention core: S + dual-activation + PV only. 4 waves, 4 heads/block,
// 2 barriers/head, q/k register prefetch, v via async global_load_lds.
// Writes ao bf16 hi/lo planes [M x 512] for proj_gemm.
__global__ __launch_bounds__(256, 4) void attn_kernel(
    const ushort_t* __restrict__ qph, const ushort_t* __restrict__ qpl,
    const ushort_t* __restrict__ kph, const ushort_t* __restrict__ kpl,
    const ushort_t* __restrict__ vph, const ushort_t* __restrict__ vpl,
    const float* __restrict__ biasM, const float* __restrict__ wbl,
    ushort_t* __restrict__ aoPh, ushort_t* __restrict__ aoPl) {
    __shared__ char a_h[8192];       // attn weights (64 rows x 128B, swizzled)
    __shared__ char a_l[8192];
    __shared__ char v_h[4096];       // vT (32 d x 128B, swizzled; gload linear)
    __shared__ char v_l[4096];

    const int blk = blockIdx.x;
    const int win = blk >> 2;
    const int q0 = (blk & 3) << 2;   // this block's 4 heads
    const int tid = threadIdx.x;
    const int l = tid & 63;
    const int w = tid >> 6;          // 0..3: n-tile owner
    const int ln = l & 15;
    const int g = l >> 4;
    const int nA = w * 16 + ln;
    const int swA = (nA & 7) << 4;

    float wb0 = wbl[0], wb1 = wbl[1];
    float wmx = fmaxf(wb0, wb1);
    float e0 = __expf(wb0 - wmx), e1 = __expf(wb1 - wmx);
    float wt0 = e0 / (e0 + e1), wt1 = e1 / (e0 + e1);

    const int offq = (w * 16 + ln) * 32 + g * 8;
    const int offk = ln * 32 + g * 8;      // + mt*512

    // initial prefetch: head q0 q/k fragments + v async->LDS
    size_t pb = ((size_t)win * 16 + q0) * 2048;
    bf16x8 nQh = *(const bf16x8*)(qph + pb + offq);
    bf16x8 nQl = *(const bf16x8*)(qpl + pb + offq);
    bf16x8 nKh[4], nKl[4];
    #pragma unroll
    for (int mt = 0; mt < 4; ++mt) {
        nKh[mt] = *(const bf16x8*)(kph + pb + offk + mt * 512);
        nKl[mt] = *(const bf16x8*)(kpl + pb + offk + mt * 512);
    }
    gload16(vph + pb + tid * 8, v_h + tid * 16);
    gload16(vpl + pb + tid * 8, v_l + tid * 16);

    #pragma unroll
    for (int hh = 0; hh < 4; ++hh) {
        const int h = q0 + hh;
        bf16x8 Qh = nQh, Ql = nQl;
        bf16x8 Kh[4], Kl[4];
        #pragma unroll
        for (int mt = 0; mt < 4; ++mt) { Kh[mt] = nKh[mt]; Kl[mt] = nKl[mt]; }

        // ---- QK^T ----
        f32x4 sv[4];
        #pragma unroll
        for (int mt = 0; mt < 4; ++mt) {
            f32x4 s = {0.f, 0.f, 0.f, 0.f};
            s = MFMA(Qh, Kh[mt], s);
            s = MFMA(Qh, Kl[mt], s);
            s = MFMA(Ql, Kh[mt], s);
            sv[mt] = s;
        }

        // prefetch next head's q/k (covered by softmax + a-store)
        if (hh < 3) {
            size_t pn = ((size_t)win * 16 + h + 1) * 2048;
            nQh = *(const bf16x8*)(qph + pn + offq);
            nQl = *(const bf16x8*)(qpl + pn + offq);
            #pragma unroll
            for (int mt = 0; mt < 4; ++mt) {
                nKh[mt] = *(const bf16x8*)(kph + pn + offk + mt * 512);
                nKl[mt] = *(const bf16x8*)(kpl + pn + offk + mt * 512);
            }
        }

        // ---- bias + dual softmax/relu^2 blend + a-store ----
        const float* bM = biasM + h * 4096;
        #pragma unroll
        for (int r = 0; r < 4; ++r) {
            int n_ = w * 16 + g * 4 + r;
            #pragma unroll
            for (int mt = 0; mt < 4; ++mt)
                sv[mt][r] += bM[n_ * 64 + mt * 16 + ln];
        }
        #pragma unroll
        for (int r = 0; r < 4; ++r) {
            int n_ = w * 16 + g * 4 + r;
            float mx = fmaxf(fmaxf(sv[0][r], sv[1][r]), fmaxf(sv[2][r], sv[3][r]));
            mx = fmaxf(mx, __shfl_xor(mx, 1));
            mx = fmaxf(mx, __shfl_xor(mx, 2));
            mx = fmaxf(mx, __shfl_xor(mx, 4));
            mx = fmaxf(mx, __shfl_xor(mx, 8));
            float ex[4];
            float sum = 0.f;
            #pragma unroll
            for (int mt = 0; mt < 4; ++mt) {
                ex[mt] = __expf(sv[mt][r] - mx);
                sum += ex[mt];
            }
            sum += __shfl_xor(sum, 1);
            sum += __shfl_xor(sum, 2);
            sum += __shfl_xor(sum, 4);
            sum += __shfl_xor(sum, 8);
            float rinv0 = wt0 / sum;
            #pragma unroll
            for (int mt = 0; mt < 4; ++mt) {
                int m_ = mt * 16 + ln;
                float rl = fmaxf(sv[mt][r], 0.f);
                float aval = ex[mt] * rinv0 + wt1 * rl * rl;
                unsigned short hv, lv;
                split2(aval, hv, lv);
                int aoff = n_ * 128 + ((2 * m_) ^ ((n_ & 7) << 4));
                *(unsigned short*)(a_h + aoff) = hv;
                *(unsigned short*)(a_l + aoff) = lv;
            }
        }
        __syncthreads();   // B1: a ready; v gload drained (vmcnt)

        // ---- PV: ao = a @ v ----
        f32x4 ao[2];
        #pragma unroll
        for (int dt = 0; dt < 2; ++dt) {
            const int dcol = dt * 16 + ln;
            const int swV = (dcol & 7) << 4;
            f32x4 o = {0.f, 0.f, 0.f, 0.f};
            #pragma unroll
            for (int ks = 0; ks < 2; ++ks) {
                int mo = 2 * (ks * 32 + g * 8);
                bf16x8 Aa = *(const bf16x8*)(a_h + nA * 128 + (mo ^ swA));
                bf16x8 Ab = *(const bf16x8*)(a_l + nA * 128 + (mo ^ swA));
                bf16x8 Vh = *(const bf16x8*)(v_h + dcol * 128 + (mo ^ swV));
                bf16x8 Vl = *(const bf16x8*)(v_l + dcol * 128 + (mo ^ swV));
                o = MFMA(Aa, Vh, o);
                o = MFMA(Aa, Vl, o);
                o = MFMA(Ab, Vh, o);
            }
            ao[dt] = o;
        }
        __syncthreads();   // B2: a/v reads done -> safe to overwrite next iter

        // issue next head's v async (lands by next B1)
        if (hh < 3) {
            size_t pn = ((size_t)win * 16 + h + 1) * 2048;
            gload16(vph + pn + tid * 8, v_h + tid * 16);
            gload16(vpl + pn + tid * 8, v_l + tid * 16);
        }

        // ---- ao -> global planes (bf16 hi/lo), fire-and-forget ----
        #pragma unroll
        for (int dt = 0; dt < 2; ++dt) {
            #pragma unroll
            for (int r = 0; r < 4; ++r) {
                int n_ = w * 16 + g * 4 + r;
                size_t o = ((size_t)win * 64 + n_) * 512 + h * 32 + dt * 16 + ln;
                unsigned short hv, lv;
                split2(ao[dt][r], hv, lv);
                aoPh[o] = hv;
                aoPl[o] = lv;
            }
        }
    }
}

extern "C" void kernel_launch(void* const* d_in, const int* in_sizes, int n_in,
                              void* d_out, int out_size, void* d_ws, size_t ws_size,
                              hipStream_t stream) {
    const float* x = (const float*)d_in[0];
    const float* Wq = (const float*)d_in[1];
    const float* bq = (const float*)d_in[2];
    const float* Wkv = (const float*)d_in[3];
    const float* bkv = (const float*)d_in[4];
    const float* btab = (const float*)d_in[5];
    const float* wbl = (const float*)d_in[6];
    const float* Wp = (const float*)d_in[7];
    const float* bp = (const float*)d_in[8];
    float* out = (float*)d_out;

    char* ws = (char*)d_ws;
    ushort_t* BTh = (ushort_t*)(ws + 0);           // 1536x512 bf16 = 1.5MB
    ushort_t* BTl = (ushort_t*)(ws + 1572864);
    ushort_t* WpTh = (ushort_t*)(ws + 3145728);
    ushort_t* WpTl = (ushort_t*)(ws + 3670016);
    float* biasM = (float*)(ws + 4194304);         // 256KB -> 4456448

    const size_t qbase = 4456448;
    // per-window: xT 128KB + q/k/v planes 384KB + ao planes 128KB = 640KB
    int npass;
    if (ws_size >= qbase + (size_t)1024 * 655360) npass = 1;       // 675MB
    else if (ws_size >= qbase + (size_t)512 * 655360) npass = 2;   // 340MB (fits >=407)
    else npass = 4;                                                // 172MB
    const int wpp = 1024 / npass;
    const size_t C = (size_t)wpp * 65536;          // one 64KB-per-window plane
    ushort_t* xTh = (ushort_t*)(ws + qbase);
    ushort_t* xTl = (ushort_t*)(ws + qbase + C);
    ushort_t* qph = (ushort_t*)(ws + qbase + 2 * C);
    ushort_t* qpl = (ushort_t*)(ws + qbase + 3 * C);
    ushort_t* kph = (ushort_t*)(ws + qbase + 4 * C);
    ushort_t* kpl = (ushort_t*)(ws + qbase + 5 * C);
    ushort_t* vph = (ushort_t*)(ws + qbase + 6 * C);
    ushort_t* vpl = (ushort_t*)(ws + qbase + 7 * C);
    ushort_t* aoPh = (ushort_t*)(ws + qbase + 8 * C);
    ushort_t* aoPl = (ushort_t*)(ws + qbase + 9 * C);

    wsplit_kernel<<<64, 256, 0, stream>>>(Wq, BTh, BTl, 512, 512);
    wsplit_kernel<<<128, 256, 0, stream>>>(Wkv, BTh + (size_t)512 * 512,
                                           BTl + (size_t)512 * 512, 512, 1024);
    wsplit_kernel<<<64, 256, 0, stream>>>(Wp, WpTh, WpTl, 512, 512);
    biasM_kernel<<<256, 256, 0, stream>>>(btab, biasM);

    (void)hipFuncSetAttribute((const void*)qkv_gemm,
                              hipFuncAttributeMaxDynamicSharedMemorySize, 65536);
    (void)hipFuncSetAttribute((const void*)proj_gemm,
                              hipFuncAttributeMaxDynamicSharedMemorySize, 65536);

    const int gm = wpp / 2;          // 128-row M-tiles per pass
    for (int p = 0; p < npass; ++p) {
        xsplit_kernel<<<wpp * 8, 256, 0, stream>>>(x + (size_t)p * wpp * 32768,
                                                   xTh, xTl);
        qkv_gemm<<<gm * 12, 256, 65536, stream>>>(xTh, xTl, BTh, BTl, bq, bkv,
                                                  qph, qpl, kph, kpl, vph, vpl,
                                                  gm);
        attn_kernel<<<wpp * 4, 256, 0, stream>>>(qph, qpl, kph, kpl, vph, vpl,
                                                 biasM, wbl, aoPh, aoPl);
        proj_gemm<<<gm * 4, 256, 65536, stream>>>(aoPh, aoPl, WpTh, WpTl, bp,
                                                  out + (size_t)p * wpp * 32768,
                                                  gm);
    }
}